// Round 8
// baseline (80.580 us; speedup 1.0000x reference)
//
#include <hip/hip_runtime.h>
#include <hip/hip_bf16.h>

#define B_ 64
#define S_ 128
#define D_ 1024
#define O_ 1024
#define L_ 16

typedef __bf16 bf16x8 __attribute__((ext_vector_type(8)));
typedef float f32x4 __attribute__((ext_vector_type(4)));

// 8 floats -> bf16x8 via scalar casts; compiler pairs these into
// v_cvt_pk_bf16_f32 (RNE) — m240: don't hand-write cvt_pk.
__device__ __forceinline__ bf16x8 cvt8(float4 a, float4 b) {
    bf16x8 r;
    r[0] = (__bf16)a.x; r[1] = (__bf16)a.y; r[2] = (__bf16)a.z; r[3] = (__bf16)a.w;
    r[4] = (__bf16)b.x; r[5] = (__bf16)b.y; r[6] = (__bf16)b.z; r[7] = (__bf16)b.w;
    return r;
}

// Single fused kernel: per-position GEMM with in-kernel fp32->bf16 staging.
// Block = (pair pi, nt). Tile M=128 (2s x 64b) x N=128, BK=64, 8 waves
// (2 wm x 4 wn), each wave 64x32 = 4x2 fragments of 16x16x32 bf16.
// Staging: reg-path (global fp32 -> cvt_pk -> XOR-swizzled ds_write_b128),
// T14 split: loads for kt+1 issued BEFORE the kt MFMA phase, LDS written
// after barrier1. In-block pair scan (no separate kernel, no workspace).
__global__ __launch_bounds__(512, 4) void moshi_fused(
    const float* __restrict__ x, const int* __restrict__ lidx,
    const float* __restrict__ w, float* __restrict__ out) {

    __shared__ __align__(16) unsigned char lw[16384];   // 128(o) x 64(k) bf16, XOR-swizzled
    __shared__ __align__(16) unsigned char lx[16384];   // s0:64 b-rows + s1:64 b-rows
    __shared__ int occ[16][128];                        // occurrence lists per layer
    __shared__ int cnts[16];

    const int tid = threadIdx.x, lane = tid & 63, wid = tid >> 6;

    // ---- in-block pair scan: lanes 0-15 each collect their layer's s-list ----
    if (tid < 16) {
        int c = 0;
        for (int s = 0; s < S_; ++s) {
            if (lidx[s] == tid) occ[tid][c++] = s;
        }
        cnts[tid] = c;
    }
    __syncthreads();

    // bijective XCD-chunk swizzle: grid 576 = 8 chunks of 72 (9 pairs x 8 nt)
    const int bid = (blockIdx.x & 7) * 72 + (blockIdx.x >> 3);
    const int pi = bid >> 3;
    const int nt = bid & 7;

    int np = 0, l = -1, j = 0;
    #pragma unroll
    for (int m = 0; m < 16; ++m) {
        int p = (cnts[m] + 1) >> 1;
        if (l < 0 && pi < np + p) { l = m; j = pi - np; }
        np += p;
    }
    if (pi >= np) return;   // block-uniform exit (after the only prior barrier)
    const int cl = cnts[l];
    const int s0 = occ[l][2 * j];
    const int s1 = occ[l][(2 * j + 1 < cl) ? (2 * j + 1) : (2 * j)];

    // ---- staging addresses ----
    // W: thread t stages row=t/4 (o), quad q=t&3 -> 16 consecutive floats.
    const int wrow = tid >> 2;
    const int q    = tid & 3;
    const float* wsrc = w + ((size_t)(l * O_ + nt * 128 + wrow)) * D_ + q * 16;
    const int key_w = (wrow & 7) << 4;
    const int c0    = q * 32;                       // bf16 byte col of this quad
    unsigned char* lw0 = lw + wrow * 128 + (c0 ^ key_w);
    unsigned char* lw1 = lw + wrow * 128 + ((c0 + 16) ^ key_w);
    // x: thread t stages s-half = t/256, b-row = (t/4)&63, quad q.
    const int shalf = tid >> 8;
    const int xb    = (tid >> 2) & 63;
    const int s_st  = shalf ? s1 : s0;
    const float* xsrc = x + ((size_t)(xb * S_ + s_st)) * D_ + q * 16;
    const int key_x = (xb & 7) << 4;
    unsigned char* lx0 = lx + shalf * 8192 + xb * 128 + (c0 ^ key_x);
    unsigned char* lx1 = lx + shalf * 8192 + xb * 128 + ((c0 + 16) ^ key_x);

    // ---- fragment read addressing (same as proven R6 kernel) ----
    const int wm = wid >> 2, wn = wid & 3;
    const int swz = (lane & 7) << 4;
    const int kb  = (lane >> 4) << 4;
    const int a_base = (wm * 64 + (lane & 15)) * 128 + kb;   // x rows
    const int b_base = (wn * 32 + (lane & 15)) * 128 + kb;   // W rows

    f32x4 acc[4][2];
    #pragma unroll
    for (int i = 0; i < 4; ++i)
        #pragma unroll
        for (int jj = 0; jj < 2; ++jj) acc[i][jj] = (f32x4)0.0f;

    // ---- prologue: stage kt=0 ----
    {
        const float4* pw = reinterpret_cast<const float4*>(wsrc);
        float4 a0 = pw[0], a1 = pw[1], a2 = pw[2], a3 = pw[3];
        const float4* px = reinterpret_cast<const float4*>(xsrc);
        float4 b0 = px[0], b1 = px[1], b2 = px[2], b3 = px[3];
        *reinterpret_cast<bf16x8*>(lw0) = cvt8(a0, a1);
        *reinterpret_cast<bf16x8*>(lw1) = cvt8(a2, a3);
        *reinterpret_cast<bf16x8*>(lx0) = cvt8(b0, b1);
        *reinterpret_cast<bf16x8*>(lx1) = cvt8(b2, b3);
    }
    __syncthreads();

    #pragma unroll 1
    for (int kt = 0; kt < 16; ++kt) {
        // 1) issue next tile's global loads (fly across the MFMA phase)
        float4 a0, a1, a2, a3, b0, b1, b2, b3;
        if (kt < 15) {
            const float4* pw = reinterpret_cast<const float4*>(wsrc + (kt + 1) * 64);
            a0 = pw[0]; a1 = pw[1]; a2 = pw[2]; a3 = pw[3];
            const float4* px = reinterpret_cast<const float4*>(xsrc + (kt + 1) * 64);
            b0 = px[0]; b1 = px[1]; b2 = px[2]; b3 = px[3];
        }
        // 2) compute from LDS
        #pragma unroll
        for (int kk = 0; kk < 2; ++kk) {
            bf16x8 af[4], bfr[2];
            #pragma unroll
            for (int mi = 0; mi < 4; ++mi)
                af[mi] = *reinterpret_cast<const bf16x8*>(
                    lx + (((a_base + kk * 64) ^ swz) + mi * 2048));
            #pragma unroll
            for (int ni = 0; ni < 2; ++ni)
                bfr[ni] = *reinterpret_cast<const bf16x8*>(
                    lw + (((b_base + kk * 64) ^ swz) + ni * 2048));
            #pragma unroll
            for (int mi = 0; mi < 4; ++mi)
                #pragma unroll
                for (int ni = 0; ni < 2; ++ni)
                    acc[mi][ni] = __builtin_amdgcn_mfma_f32_16x16x32_bf16(
                        af[mi], bfr[ni], acc[mi][ni], 0, 0, 0);
        }
        if (kt == 15) break;
        __syncthreads();   // all waves done reading LDS(kt); drains loads too
        // 3) convert + write next tile
        *reinterpret_cast<bf16x8*>(lw0) = cvt8(a0, a1);
        *reinterpret_cast<bf16x8*>(lw1) = cvt8(a2, a3);
        *reinterpret_cast<bf16x8*>(lx0) = cvt8(b0, b1);
        *reinterpret_cast<bf16x8*>(lx1) = cvt8(b2, b3);
        __syncthreads();   // LDS(kt+1) visible
    }

    // ---- epilogue: C/D col = lane&15 (o), row = (lane>>4)*4 + reg (b) ----
    const int s_sel = wm ? s1 : s0;
    const int col0 = nt * 128 + wn * 32 + (lane & 15);
    const int r0 = (lane >> 4) << 2;
    #pragma unroll
    for (int mi = 0; mi < 4; ++mi)
        #pragma unroll
        for (int ni = 0; ni < 2; ++ni)
            #pragma unroll
            for (int r = 0; r < 4; ++r) {
                int b = mi * 16 + r0 + r;
                out[((size_t)b * S_ + s_sel) * O_ + col0 + ni * 16] = acc[mi][ni][r];
            }
}

extern "C" void kernel_launch(void* const* d_in, const int* in_sizes, int n_in,
                              void* d_out, int out_size, void* d_ws, size_t ws_size,
                              hipStream_t stream) {
    const float* x  = (const float*)d_in[0];
    const int* lidx = (const int*)d_in[1];
    const float* w  = (const float*)d_in[2];
    float* out      = (float*)d_out;
    (void)d_ws; (void)ws_size;
    // 72 pair slots x 8 n-tiles; blocks beyond npairs exit early
    moshi_fused<<<dim3(72 * 8), dim3(512), 0, stream>>>(x, lidx, w, out);
}